// Round 1
// 584.321 us; speedup vs baseline: 1.0037x; 1.0037x over previous
//
#include <hip/hip_runtime.h>

// Problem: h[t] = a[t]*h[t-1] + b[t] along axis S of (B,S,D,N) = (2,2048,1024,16), fp32.
// 32768 independent chains (one per (b,d,n)), scan stride = D*N elements.
//
// R1: ping-pong double buffer (no rotation copies) + sched_barrier fences.
// The previous version's rotate-buffer structure let the compiler sink the
// prefetch loads to the rotation point (VGPR_Count=40 proves buffers were not
// register-resident), collapsing the pipeline to ~zero lookahead ->
// latency-bound at 2.7 TB/s. Here buffers A/B alternate by name (compile-time),
// so no copies exist to rename away, and __builtin_amdgcn_sched_barrier(0)
// pins the load-issue blocks ahead of the compute blocks. While computing one
// half (16 serial fma + stores), the other half's 32 loads stay in flight.

constexpr int S_LEN         = 2048;
constexpr int DN            = 1024 * 16;          // 16384 chains per batch
constexpr long BATCH_STRIDE = (long)S_LEN * DN;   // elements per batch
constexpr int NCHAIN        = 2 * DN;             // 32768 total chains
constexpr int U             = 16;                 // half-depth (steps per ping-pong half)

__global__ __launch_bounds__(64) void scan_chain_kernel(
    const float* __restrict__ a,
    const float* __restrict__ b,
    float* __restrict__ out)
{
    const int m  = blockIdx.x * 64 + threadIdx.x;   // chain id, 0..32767
    const int bi = m >> 14;                          // m / DN
    const int dn = m & (DN - 1);                     // m % DN
    const size_t base = (size_t)bi * BATCH_STRIDE + dn;

    const float* __restrict__ ap = a + base;
    const float* __restrict__ bp = b + base;
    float* __restrict__ op = out + base;

    float aA[U], bA[U], aB[U], bB[U];

    // Preload first half into A.
    #pragma unroll
    for (int u = 0; u < U; ++u) {
        aA[u] = ap[(size_t)u * DN];
        bA[u] = bp[(size_t)u * DN];
    }

    float h = 0.0f;
    // 2U steps per iteration; S_LEN % (2U) == 0 -> 64 iterations, no tail.
    for (int s0 = 0; s0 < S_LEN; s0 += 2 * U) {
        // Issue loads for steps [s0+U, s0+2U) into B (always in range: s0+2U <= S_LEN).
        {
            const float* __restrict__ ap2 = ap + (size_t)(s0 + U) * DN;
            const float* __restrict__ bp2 = bp + (size_t)(s0 + U) * DN;
            #pragma unroll
            for (int u = 0; u < U; ++u) {
                aB[u] = ap2[(size_t)u * DN];
                bB[u] = bp2[(size_t)u * DN];
            }
        }
        __builtin_amdgcn_sched_barrier(0);  // keep B-loads issued before A-compute

        // Compute steps [s0, s0+U) from A; coalesced stores.
        {
            float* __restrict__ op2 = op + (size_t)s0 * DN;
            #pragma unroll
            for (int u = 0; u < U; ++u) {
                h = fmaf(aA[u], h, bA[u]);
                op2[(size_t)u * DN] = h;
            }
        }
        __builtin_amdgcn_sched_barrier(0);

        // Issue loads for steps [s0+2U, s0+3U) into A (skip on last iteration).
        if (s0 + 2 * U < S_LEN) {
            const float* __restrict__ ap2 = ap + (size_t)(s0 + 2 * U) * DN;
            const float* __restrict__ bp2 = bp + (size_t)(s0 + 2 * U) * DN;
            #pragma unroll
            for (int u = 0; u < U; ++u) {
                aA[u] = ap2[(size_t)u * DN];
                bA[u] = bp2[(size_t)u * DN];
            }
        }
        __builtin_amdgcn_sched_barrier(0);  // keep A-loads issued before B-compute

        // Compute steps [s0+U, s0+2U) from B.
        {
            float* __restrict__ op2 = op + (size_t)(s0 + U) * DN;
            #pragma unroll
            for (int u = 0; u < U; ++u) {
                h = fmaf(aB[u], h, bB[u]);
                op2[(size_t)u * DN] = h;
            }
        }
        __builtin_amdgcn_sched_barrier(0);
    }
}

extern "C" void kernel_launch(void* const* d_in, const int* in_sizes, int n_in,
                              void* d_out, int out_size, void* d_ws, size_t ws_size,
                              hipStream_t stream) {
    const float* a = (const float*)d_in[0];
    const float* b = (const float*)d_in[1];
    float* out = (float*)d_out;

    dim3 grid(NCHAIN / 64);   // 512 blocks
    dim3 block(64);           // 1 wave each -> 2 waves/CU across 256 CUs
    scan_chain_kernel<<<grid, block, 0, stream>>>(a, b, out);
}

// Round 2
// 584.226 us; speedup vs baseline: 1.0038x; 1.0002x over previous
//
#include <hip/hip_runtime.h>

// h[t] = a[t]*h[t-1] + b[t] along S of (B,S,D,N) = (2,2048,1024,16) fp32.
// 32768 chains, contiguous along (d,n); scan stride DN between steps.
//
// R2: global_load_lds staging. R0/R1 proved the compiler won't hold a deep
// register-resident prefetch (VGPR 40/64, eff. ~8-20 loads in flight ->
// 2.7 TB/s latency-bound). Here in-flight bytes are decoupled from VGPRs:
//   - 256-chain blocks (4 waves) so one global_load_lds_dwordx4 stages 1 KB
//   - 4 LDS buffers x [T=8][a|b][256] = exactly 64 KB static
//   - 3-tiles-ahead pipeline, raw s_barrier + counted s_waitcnt vmcnt(N)
//     (NOT __syncthreads(): it drains vmcnt(0) and re-collapses the pipe)
// In-flight reads: 128 blocks x 3 tiles x 16 KB ~ 6 MB >> 2.4-5.7 MB needed
// for 6.3 TB/s at 375-900 ns latency.
//
// vmcnt accounting (per wave, in-order retirement; stage=4 loads/tile,
// stores=8/tile, all count in vmcnt):
//   ops younger than stage(k)'s last load =
//     stores(k-3) + stage(k+1) + stores(k-2) + stage(k+2) + stores(k-1)
//     = 8+4+8+4+8 = 32 in steady state; 8/16/24 during prologue; <=24 at tail.
//   vmcnt(N) with N <= that count is always safe (outstanding set is a
//   youngest-suffix of issue order).

constexpr int S_LEN = 2048;
constexpr int DN = 1024 * 16;                        // chains per batch
constexpr long long BATCH_STRIDE = (long long)S_LEN * DN;
constexpr int CPB  = 256;                            // chains per block
constexpr int T    = 8;                              // steps per tile
constexpr int NBUF = 4;                              // LDS buffers (64 KB total)
constexpr int NT   = S_LEN / T;                      // 256 tiles
constexpr int NBLOCKS = (2 * DN) / CPB;              // 128

template<int N>
__device__ __forceinline__ void vmwait() {
    asm volatile("s_waitcnt vmcnt(%0)" :: "n"(N) : "memory");
}

__device__ __forceinline__ void gload_lds16(const float* g, float* l) {
    __builtin_amdgcn_global_load_lds(
        (const __attribute__((address_space(1))) void*)g,
        (__attribute__((address_space(3))) void*)l,
        16 /*bytes per lane, literal*/, 0, 0);
}

__global__ __launch_bounds__(256) void scan_lds_kernel(
    const float* __restrict__ a,
    const float* __restrict__ b,
    float* __restrict__ out)
{
    __shared__ float lds[NBUF * 2 * T * CPB];        // 4*2*8*256*4 B = 64 KB

    const int tid  = threadIdx.x;
    const int lane = tid & 63;
    const int wave = tid >> 6;                        // 0..3
    const int bi     = blockIdx.x >> 6;               // 64 blocks per batch
    const int chain0 = (blockIdx.x & 63) * CPB;

    const size_t gband = (size_t)bi * BATCH_STRIDE + chain0;
    const float* __restrict__ ga = a + gband;
    const float* __restrict__ gb = b + gband;
    float* __restrict__ go = out + gband + tid;       // this thread's chain

    // Wave w stages steps {2w, 2w+1} of a tile: 4 x 1 KB DMA per wave per tile.
    auto stage = [&](int tile) {
        float* lb = &lds[(tile & (NBUF - 1)) * (2 * T * CPB)];
        const size_t s0 = (size_t)tile * T;
        #pragma unroll
        for (int j = 0; j < 2; ++j) {
            const int u = 2 * wave + j;
            const size_t roff = (s0 + u) * (size_t)DN + (size_t)lane * 4;
            gload_lds16(ga + roff, &lb[u * CPB]);           // a-plane row u
            gload_lds16(gb + roff, &lb[(T + u) * CPB]);     // b-plane row u
        }
    };

    stage(0); stage(1); stage(2);                     // prime 3 tiles

    float h = 0.0f;
    for (int k = 0; k < NT; ++k) {
        // Wait for own contribution to tile k (exact-count, never drain to 0).
        if      (k == 0)      vmwait<8>();
        else if (k == 1)      vmwait<16>();
        else if (k == 2)      vmwait<24>();
        else if (k >= NT - 2) vmwait<24>();
        else                  vmwait<32>();
        __builtin_amdgcn_s_barrier();                 // all waves' tile-k parts done;
        __builtin_amdgcn_sched_barrier(0);            // fence scheduler motion (rule #18)

        // Refill the buffer compute(k-1) just vacated ((k+3)%4 == (k-1)%4).
        if (k + 3 < NT) stage(k + 3);

        // Consume tile k: serial recurrence, coalesced 1 KB/step stores.
        const float* lb = &lds[(k & (NBUF - 1)) * (2 * T * CPB)];
        float* orow = go + (size_t)k * T * DN;
        #pragma unroll
        for (int u = 0; u < T; ++u) {
            h = fmaf(lb[u * CPB + tid], h, lb[(T + u) * CPB + tid]);
            orow[(size_t)u * DN] = h;
        }
    }
}

extern "C" void kernel_launch(void* const* d_in, const int* in_sizes, int n_in,
                              void* d_out, int out_size, void* d_ws, size_t ws_size,
                              hipStream_t stream) {
    const float* a = (const float*)d_in[0];
    const float* b = (const float*)d_in[1];
    float* out = (float*)d_out;

    dim3 grid(NBLOCKS);    // 128 blocks -> <=1 block/CU, 4 waves each
    dim3 block(CPB);       // 256 threads
    scan_lds_kernel<<<grid, block, 0, stream>>>(a, b, out);
}